// Round 6
// baseline (65.222 us; speedup 1.0000x reference)
//
#include <hip/hip_runtime.h>
#include <stdint.h>
#include <stddef.h>

// ---- problem constants ----
#define NBATCH 2
#define NPTS   120000
#define T_SLOTS 100
#define PMAX   12000
#define NXG    500
#define NYG    500
#define NBINS  (NXG*NYG)     // 250000
#define SCAN_B 512
#define NBLK   ((NBINS + SCAN_B - 1)/SCAN_B)   // 489

#define FEAT_BLOCKS 2000     // x4 waves = 8000 waves x 3 pillars = 24000 exactly
#define NWAVES     (FEAT_BLOCKS*4)

// ---- workspace layout (bytes) ----
#define WS_CNT     ((size_t)0)                                   // 2*NBINS*4
#define WS_SLOT    (WS_CNT   + (size_t)NBATCH*NBINS*4)           // 2*PMAX*4
#define WS_ZEROEND (WS_SLOT  + (size_t)NBATCH*PMAX*4)            // zero region = 2,096,000 B
#define WS_RANK    (WS_ZEROEND)                                   // 2*NBINS*4
#define WS_KEYPT   (WS_RANK  + (size_t)NBATCH*NBINS*4)           // 2*NPTS*4
#define WS_PMETA   (WS_KEYPT + (size_t)NBATCH*NPTS*4)            // 2*PMAX*8 (int2: key,cnt)
#define WS_PIDX    (WS_PMETA + (size_t)NBATCH*PMAX*8)            // 2*PMAX*T*4
#define WS_BSUM    (WS_PIDX  + (size_t)NBATCH*PMAX*T_SLOTS*4)    // 2*512*4
#define WS_PTOT    (WS_BSUM  + (size_t)NBATCH*SCAN_B*4)          // 2*4
#define WS_NEEDED  (WS_PTOT  + (size_t)NBATCH*4)

#define ZERO_F4    (WS_ZEROEND / 16)     // 131,000 float4s

// ---------------- kernels ----------------

__global__ void k_zero(float4* __restrict__ dst) {
    int i = blockIdx.x * blockDim.x + threadIdx.x;
    if (i < (int)ZERO_F4) {
        float4 z; z.x = 0.0f; z.y = 0.0f; z.z = 0.0f; z.w = 0.0f;
        dst[i] = z;
    }
}

__global__ void k_key(const float* __restrict__ pts, int* __restrict__ keypt,
                      int* __restrict__ cnt) {
    int i = blockIdx.x * blockDim.x + threadIdx.x;
    if (i >= NBATCH * NPTS) return;
    int b = i / NPTS;
    const float* p = pts + (size_t)i * 4;
    float x = p[0], y = p[1], z = p[2];
    bool valid = (x >= -40.0f) && (x < 40.0f) &&
                 (y >= -40.0f) && (y < 40.0f) &&
                 (z >= -3.0f)  && (z < 1.0f);
    int key = -1;
    if (valid) {
        float fx = floorf((x - (-40.0f)) / 0.16f);
        float fy = floorf((y - (-40.0f)) / 0.16f);
        fx = fminf(fmaxf(fx, 0.0f), (float)(NXG - 1));
        fy = fminf(fmaxf(fy, 0.0f), (float)(NYG - 1));
        key = (int)fx * NYG + (int)fy;
        atomicAdd(&cnt[b * NBINS + key], 1);
    }
    keypt[i] = key;
}

__global__ void k_scan1(const int* __restrict__ cnt, int* __restrict__ bsum) {
    __shared__ int sh[SCAN_B];
    int b = blockIdx.y;
    int bin = blockIdx.x * SCAN_B + threadIdx.x;
    int pres = (bin < NBINS && cnt[b * NBINS + bin] > 0) ? 1 : 0;
    sh[threadIdx.x] = pres;
    __syncthreads();
    for (int s = SCAN_B / 2; s > 0; s >>= 1) {
        if (threadIdx.x < s) sh[threadIdx.x] += sh[threadIdx.x + s];
        __syncthreads();
    }
    if (threadIdx.x == 0) bsum[b * SCAN_B + blockIdx.x] = sh[0];
}

// fused scan2+scan3
__global__ void k_scan23(const int* __restrict__ cnt, const int* __restrict__ bsum,
                         int* __restrict__ rank, int* __restrict__ ptot) {
    __shared__ int shb[SCAN_B];
    __shared__ int sh[SCAN_B];
    int b = blockIdx.y;
    int tid = threadIdx.x;

    int v = (tid < NBLK) ? bsum[b * SCAN_B + tid] : 0;
    shb[tid] = v;
    __syncthreads();
    for (int s = 1; s < SCAN_B; s <<= 1) {
        int t = (tid >= s) ? shb[tid - s] : 0;
        __syncthreads();
        shb[tid] += t;
        __syncthreads();
    }

    int bin = blockIdx.x * SCAN_B + tid;
    int pres = (bin < NBINS && cnt[b * NBINS + bin] > 0) ? 1 : 0;
    sh[tid] = pres;
    __syncthreads();
    for (int s = 1; s < SCAN_B; s <<= 1) {
        int t = (tid >= s) ? sh[tid - s] : 0;
        __syncthreads();
        sh[tid] += t;
        __syncthreads();
    }
    if (bin < NBINS) {
        int boff = blockIdx.x ? shb[blockIdx.x - 1] : 0;
        rank[b * NBINS + bin] = boff + sh[tid] - pres;
    }
    if (blockIdx.x == 0 && tid == 0) ptot[b] = shb[NBLK - 1];
}

__global__ void k_fill(const int* __restrict__ keypt, const int* __restrict__ cnt,
                       const int* __restrict__ rank, int* __restrict__ slotctr,
                       int2* __restrict__ pmeta, int* __restrict__ pidx) {
    int i = blockIdx.x * blockDim.x + threadIdx.x;
    if (i >= NBATCH * NPTS) return;
    int key = keypt[i];
    if (key < 0) return;
    int b = i / NPTS;
    int j = i - b * NPTS;
    int c = cnt[b * NBINS + key];
    int r = rank[b * NBINS + key];
    if (r >= PMAX) return;
    int2 m; m.x = key; m.y = c;
    pmeta[b * PMAX + r] = m;      // all writers store the same value
    if (c <= T_SLOTS) {
        int t = atomicAdd(&slotctr[b * PMAX + r], 1);
        pidx[((size_t)(b * PMAX + r)) * T_SLOTS + t] = j;
    } else {
        // rare overflow pillar: exact first-T-by-original-index selection
        const int* kp = keypt + (size_t)b * NPTS;
        int intra = 0;
        for (int q = 0; q < j; ++q) intra += (kp[q] == key);
        if (intra < T_SLOTS)
            pidx[((size_t)(b * PMAX + r)) * T_SLOTS + intra] = j;
    }
}

// Each wave owns exactly 3 pillars (p, p+8000, p+16000) and processes slot s
// of all 3 per pass: one 16B w2s read feeds 3x4 FMAs -> LDS w2 traffic /3.
// All small arrays fully-unrolled static indexing (stay in VGPRs).
__global__ __launch_bounds__(256, 4)
void k_feats(const float4* __restrict__ pts4,
             const float* __restrict__ w1, const float* __restrict__ g1,
             const float* __restrict__ b1, const float* __restrict__ m1,
             const float* __restrict__ v1,
             const float* __restrict__ w2, const float* __restrict__ g2,
             const float* __restrict__ b2, const float* __restrict__ m2,
             const float* __restrict__ v2,
             const int2* __restrict__ pmeta,
             const int* __restrict__ pidx, const int* __restrict__ ptot,
             float* __restrict__ out) {
    __shared__ float4 w2s[16 * 64];                 // [kq][o], 16 KB
    __shared__ __align__(16) float h1s[4][3][64];   // [wave][pillar][channel], 3 KB

    const int tid  = threadIdx.x;
    const int lane = tid & 63;
    const int widx = tid >> 6;
    const int o = lane;

    float* feats  = out;                                   // [B][PMAX][64]
    float* coords = out + (size_t)NBATCH * PMAX * 64;      // [B][PMAX][3]

    // ---- layer-1 folded weights (8 regs) ----
    float s1 = g1[o] * rsqrtf(v1[o] + 1e-5f);
    float b1f = b1[o] - m1[o] * s1;
    float w1r[8];
    {
        const float4* w14 = (const float4*)(w1 + o * 8);
        float4 a = w14[0], c4 = w14[1];
        w1r[0] = a.x * s1;  w1r[1] = a.y * s1;  w1r[2] = a.z * s1;  w1r[3] = a.w * s1;
        w1r[4] = c4.x * s1; w1r[5] = c4.y * s1; w1r[6] = c4.z * s1; w1r[7] = c4.w * s1;
    }

    // ---- stage folded w2 into LDS ----
    float s2 = g2[o] * rsqrtf(v2[o] + 1e-5f);
    float b2f = b2[o] - m2[o] * s2;
    {
        const float4* w2row = (const float4*)(w2 + o * 64);
        #pragma unroll
        for (int it = 0; it < 4; ++it) {
            int kq = widx + it * 4;
            float4 t = w2row[kq];
            t.x *= s2; t.y *= s2; t.z *= s2; t.w *= s2;
            w2s[kq * 64 + o] = t;
        }
    }
    __syncthreads();   // one-time; all waves converged

    int pe0 = ptot[0]; if (pe0 > PMAX) pe0 = PMAX;
    int pe1 = ptot[1]; if (pe1 > PMAX) pe1 = PMAX;

    const int gw = blockIdx.x * 4 + widx;   // 0..7999

    // ---- per-pillar state (static arrays, fully unrolled) ----
    int   p_[3], bb_[3], xi_[3], yi_[3], pc_[3], nIt_[3];
    float xc_[3], yc_[3];
    const int* prow_[3];
    #pragma unroll
    for (int i = 0; i < 3; ++i) {
        int p = gw + i * NWAVES;
        p_[i] = p;
        int b = p / PMAX;  bb_[i] = b;
        int r = p - b * PMAX;
        int pe = b ? pe1 : pe0;
        if (r >= pe) {   // wave-uniform; safety (pt_eff is typically PMAX)
            pc_[i] = 0; nIt_[i] = 0; xi_[i] = 0; yi_[i] = 0;
            xc_[i] = 0.0f; yc_[i] = 0.0f; prow_[i] = pidx;
        } else {
            int2 m = pmeta[p];
            int key = m.x, c = m.y;
            int xi = key / NYG;
            int yi = key - xi * NYG;
            xi_[i] = xi; yi_[i] = yi;
            xc_[i] = (float)xi * 0.16f - 40.0f + 0.08f;
            yc_[i] = (float)yi * 0.16f - 40.0f + 0.08f;
            int pc = (c < T_SLOTS) ? c : T_SLOTS;
            pc_[i] = pc;
            nIt_[i] = pc + ((c < T_SLOTS) ? 1 : 0);
            prow_[i] = pidx + (size_t)p * T_SLOTS;
        }
    }

    int maxN = nIt_[0];
    if (nIt_[1] > maxN) maxN = nIt_[1];
    if (nIt_[2] > maxN) maxN = nIt_[2];

    float acc0 = 0.0f, acc1 = 0.0f, acc2 = 0.0f;

    for (int s = 0; s < maxN; ++s) {
        // phase A: h1 for slot s of each pillar (padding slots use P=0; discarded later)
        #pragma unroll
        for (int i = 0; i < 3; ++i) {
            float4 P;
            if (s < pc_[i]) {
                int j = prow_[i][s];
                P = pts4[(size_t)bb_[i] * NPTS + j];
            } else {
                P.x = 0.0f; P.y = 0.0f; P.z = 0.0f; P.w = 0.0f;
            }
            float h = b1f;
            h += w1r[0] * P.x; h += w1r[1] * P.y;
            h += w1r[2] * P.z; h += w1r[3] * P.w;
            h += w1r[4] * xc_[i]; h += w1r[5] * yc_[i];
            h += w1r[6] * (P.x - xc_[i]); h += w1r[7] * (P.y - yc_[i]);
            h1s[widx][i][o] = fmaxf(h, 0.0f);
        }
        asm volatile("s_waitcnt lgkmcnt(0)" ::: "memory");

        // phase B: one w2 quad read serves all 3 pillars
        float a0 = b2f, a1 = b2f, a2 = b2f;
        #pragma unroll
        for (int kq = 0; kq < 16; ++kq) {
            float4 w  = w2s[kq * 64 + o];
            float4 q0 = *(const float4*)&h1s[widx][0][kq * 4];
            float4 q1 = *(const float4*)&h1s[widx][1][kq * 4];
            float4 q2 = *(const float4*)&h1s[widx][2][kq * 4];
            a0 += w.x * q0.x; a0 += w.y * q0.y; a0 += w.z * q0.z; a0 += w.w * q0.w;
            a1 += w.x * q1.x; a1 += w.y * q1.y; a1 += w.z * q1.z; a1 += w.w * q1.w;
            a2 += w.x * q2.x; a2 += w.y * q2.y; a2 += w.z * q2.z; a2 += w.w * q2.w;
        }
        if (s < nIt_[0]) acc0 = fmaxf(acc0, fmaxf(a0, 0.0f));
        if (s < nIt_[1]) acc1 = fmaxf(acc1, fmaxf(a1, 0.0f));
        if (s < nIt_[2]) acc2 = fmaxf(acc2, fmaxf(a2, 0.0f));
    }

    // epilogue: 3 pillars
    #pragma unroll
    for (int i = 0; i < 3; ++i) {
        float acc = (i == 0) ? acc0 : (i == 1) ? acc1 : acc2;
        feats[(size_t)p_[i] * 64 + o] = acc;
        if (o < 3) {
            float cv = (o == 0) ? (float)bb_[i]
                     : (o == 1) ? (float)xi_[i] : (float)yi_[i];
            coords[(size_t)p_[i] * 3 + o] = cv;
        }
    }
}

// ---------------- launcher ----------------

extern "C" void kernel_launch(void* const* d_in, const int* in_sizes, int n_in,
                              void* d_out, int out_size, void* d_ws, size_t ws_size,
                              hipStream_t stream) {
    if (ws_size < WS_NEEDED) return;   // safety: avoid scratch corruption

    const float* pts = (const float*)d_in[0];
    const float* w1  = (const float*)d_in[1];
    const float* g1  = (const float*)d_in[2];
    const float* b1  = (const float*)d_in[3];
    const float* m1  = (const float*)d_in[4];
    const float* v1  = (const float*)d_in[5];
    const float* w2  = (const float*)d_in[6];
    const float* g2  = (const float*)d_in[7];
    const float* b2  = (const float*)d_in[8];
    const float* m2  = (const float*)d_in[9];
    const float* v2  = (const float*)d_in[10];

    char* ws = (char*)d_ws;
    int*  cnt     = (int*)(ws + WS_CNT);
    int*  slotctr = (int*)(ws + WS_SLOT);
    int*  rank    = (int*)(ws + WS_RANK);
    int*  keypt   = (int*)(ws + WS_KEYPT);
    int2* pmeta   = (int2*)(ws + WS_PMETA);
    int*  pidx    = (int*)(ws + WS_PIDX);
    int*  bsum    = (int*)(ws + WS_BSUM);
    int*  ptot    = (int*)(ws + WS_PTOT);

    float* out = (float*)d_out;

    hipLaunchKernelGGL(k_zero, dim3((ZERO_F4 + 255) / 256), dim3(256), 0, stream,
                       (float4*)(ws + WS_CNT));

    int npt = NBATCH * NPTS;
    dim3 blk256(256);
    dim3 grdPts((npt + 255) / 256);
    hipLaunchKernelGGL(k_key, grdPts, blk256, 0, stream, pts, keypt, cnt);

    dim3 grdScan(NBLK, NBATCH);
    hipLaunchKernelGGL(k_scan1, grdScan, dim3(SCAN_B), 0, stream, cnt, bsum);
    hipLaunchKernelGGL(k_scan23, grdScan, dim3(SCAN_B), 0, stream, cnt, bsum, rank, ptot);

    hipLaunchKernelGGL(k_fill, grdPts, blk256, 0, stream,
                       keypt, cnt, rank, slotctr, pmeta, pidx);

    hipLaunchKernelGGL(k_feats, dim3(FEAT_BLOCKS), blk256, 0, stream,
                       (const float4*)pts, w1, g1, b1, m1, v1, w2, g2, b2, m2, v2,
                       pmeta, pidx, ptot, out);
}

// Round 7
// 61.622 us; speedup vs baseline: 1.0584x; 1.0584x over previous
//
#include <hip/hip_runtime.h>
#include <stdint.h>
#include <stddef.h>

// ---- problem constants ----
#define NBATCH 2
#define NPTS   120000
#define T_SLOTS 100
#define PMAX   12000
#define NXG    500
#define NYG    500
#define NBINS  (NXG*NYG)     // 250000
#define SCAN_B 512
#define NBLK   ((NBINS + SCAN_B - 1)/SCAN_B)   // 489

#define FEAT_BLOCKS 6000     // x4 waves = 24000 waves = 1 wave per pillar

// ---- workspace layout (bytes) ----
#define WS_CNT     ((size_t)0)                                   // 2*NBINS*4
#define WS_SLOT    (WS_CNT   + (size_t)NBATCH*NBINS*4)           // 2*PMAX*4
#define WS_ZEROEND (WS_SLOT  + (size_t)NBATCH*PMAX*4)            // zero region = 2,096,000 B
#define WS_RANK    (WS_ZEROEND)                                   // 2*NBINS*4
#define WS_KEYPT   (WS_RANK  + (size_t)NBATCH*NBINS*4)           // 2*NPTS*4
#define WS_PMETA   (WS_KEYPT + (size_t)NBATCH*NPTS*4)            // 2*PMAX*8 (int2: key,cnt)
#define WS_PIDX    (WS_PMETA + (size_t)NBATCH*PMAX*8)            // 2*PMAX*T*4
#define WS_BSUM    (WS_PIDX  + (size_t)NBATCH*PMAX*T_SLOTS*4)    // 2*512*4
#define WS_PTOT    (WS_BSUM  + (size_t)NBATCH*SCAN_B*4)          // 2*4
#define WS_NEEDED  (WS_PTOT  + (size_t)NBATCH*4)

#define ZERO_F4    (WS_ZEROEND / 16)     // 131,000 float4s

// ---------------- kernels ----------------

__global__ void k_zero(float4* __restrict__ dst) {
    int i = blockIdx.x * blockDim.x + threadIdx.x;
    if (i < (int)ZERO_F4) {
        float4 z; z.x = 0.0f; z.y = 0.0f; z.z = 0.0f; z.w = 0.0f;
        dst[i] = z;
    }
}

__global__ void k_key(const float* __restrict__ pts, int* __restrict__ keypt,
                      int* __restrict__ cnt) {
    int i = blockIdx.x * blockDim.x + threadIdx.x;
    if (i >= NBATCH * NPTS) return;
    int b = i / NPTS;
    const float* p = pts + (size_t)i * 4;
    float x = p[0], y = p[1], z = p[2];
    bool valid = (x >= -40.0f) && (x < 40.0f) &&
                 (y >= -40.0f) && (y < 40.0f) &&
                 (z >= -3.0f)  && (z < 1.0f);
    int key = -1;
    if (valid) {
        float fx = floorf((x - (-40.0f)) / 0.16f);
        float fy = floorf((y - (-40.0f)) / 0.16f);
        fx = fminf(fmaxf(fx, 0.0f), (float)(NXG - 1));
        fy = fminf(fmaxf(fy, 0.0f), (float)(NYG - 1));
        key = (int)fx * NYG + (int)fy;
        atomicAdd(&cnt[b * NBINS + key], 1);
    }
    keypt[i] = key;
}

// block presence-sum via ballot (1 barrier)
__global__ void k_scan1(const int* __restrict__ cnt, int* __restrict__ bsum) {
    __shared__ int ws[8];
    int b = blockIdx.y;
    int tid = threadIdx.x;
    int bin = blockIdx.x * SCAN_B + tid;
    int pres = (bin < NBINS && cnt[b * NBINS + bin] > 0) ? 1 : 0;
    unsigned long long m = __ballot(pres);
    if ((tid & 63) == 0) ws[tid >> 6] = __popcll(m);
    __syncthreads();
    if (tid == 0) {
        int s = 0;
        #pragma unroll
        for (int i = 0; i < 8; ++i) s += ws[i];
        bsum[b * SCAN_B + blockIdx.x] = s;
    }
}

// fused scan2+scan3, ballot edition:
// boff = sum(bsum[t<bx]) via masked wave reduction; per-bin rank via
// ballot lane-prefix + per-wave offsets. ~2 barriers total.
__global__ void k_scan23(const int* __restrict__ cnt, const int* __restrict__ bsum,
                         int* __restrict__ rank, int* __restrict__ ptot) {
    __shared__ int redm[8], redt[8], wtots[8];
    int b   = blockIdx.y;
    int bx  = blockIdx.x;
    int tid = threadIdx.x;
    int lane = tid & 63;
    int wid  = tid >> 6;

    // block-offset + total via reduction over the 489 block sums
    int v  = (tid < NBLK) ? bsum[b * SCAN_B + tid] : 0;
    int vm = (tid < bx) ? v : 0;
    #pragma unroll
    for (int off = 32; off > 0; off >>= 1) {
        vm += __shfl_xor(vm, off);
        v  += __shfl_xor(v,  off);
    }
    if (lane == 0) { redm[wid] = vm; redt[wid] = v; }

    // presence ballot for this block's bins
    int bin = bx * SCAN_B + tid;
    int pres = (bin < NBINS && cnt[b * NBINS + bin] > 0) ? 1 : 0;
    unsigned long long m = __ballot(pres);
    int lanepre = __popcll(m & ((1ULL << lane) - 1ULL));
    if (lane == 0) wtots[wid] = __popcll(m);
    __syncthreads();

    int boff = 0, tot = 0;
    #pragma unroll
    for (int i = 0; i < 8; ++i) { boff += redm[i]; tot += redt[i]; }
    int woff = 0;
    for (int i = 0; i < wid; ++i) woff += wtots[i];

    if (bin < NBINS)
        rank[b * NBINS + bin] = boff + woff + lanepre;
    if (bx == 0 && tid == 0) ptot[b] = tot;
}

__global__ void k_fill(const int* __restrict__ keypt, const int* __restrict__ cnt,
                       const int* __restrict__ rank, int* __restrict__ slotctr,
                       int2* __restrict__ pmeta, int* __restrict__ pidx) {
    int i = blockIdx.x * blockDim.x + threadIdx.x;
    if (i >= NBATCH * NPTS) return;
    int key = keypt[i];
    if (key < 0) return;
    int b = i / NPTS;
    int j = i - b * NPTS;
    int c = cnt[b * NBINS + key];
    int r = rank[b * NBINS + key];
    if (r >= PMAX) return;
    int2 m; m.x = key; m.y = c;
    pmeta[b * PMAX + r] = m;      // all writers store the same value
    if (c <= T_SLOTS) {
        int t = atomicAdd(&slotctr[b * PMAX + r], 1);
        pidx[((size_t)(b * PMAX + r)) * T_SLOTS + t] = j;
    } else {
        // rare overflow pillar: exact first-T-by-original-index selection
        const int* kp = keypt + (size_t)b * NPTS;
        int intra = 0;
        for (int q = 0; q < j; ++q) intra += (kp[q] == key);
        if (intra < T_SLOTS)
            pidx[((size_t)(b * PMAX + r)) * T_SLOTS + intra] = j;
    }
}

// ONE pillar per wave, 24000 waves. Short dependent-load chain per wave
// (pmeta and j4 issued independently), LDS-resident folded w2.
__global__ __launch_bounds__(256, 4)
void k_feats(const float4* __restrict__ pts4,
             const float* __restrict__ w1, const float* __restrict__ g1,
             const float* __restrict__ b1, const float* __restrict__ m1,
             const float* __restrict__ v1,
             const float* __restrict__ w2, const float* __restrict__ g2,
             const float* __restrict__ b2, const float* __restrict__ m2,
             const float* __restrict__ v2,
             const int2* __restrict__ pmeta,
             const int* __restrict__ pidx, const int* __restrict__ ptot,
             float* __restrict__ out) {
    __shared__ float4 w2s[16 * 64];                 // [kq][o], 16 KB
    __shared__ __align__(16) float h1s[4][64];      // [wave][channel]

    const int tid  = threadIdx.x;
    const int lane = tid & 63;
    const int widx = tid >> 6;
    const int o = lane;

    float* feats  = out;                                   // [B][PMAX][64]
    float* coords = out + (size_t)NBATCH * PMAX * 64;      // [B][PMAX][3]

    const int p = blockIdx.x * 4 + widx;   // 0..23999, exactly one pillar
    const int b = p / PMAX;
    const int r = p - b * PMAX;

    // issue independent loads early
    const int* prow = pidx + (size_t)p * T_SLOTS;
    int2 meta = pmeta[p];
    int4 j4 = *(const int4*)prow;          // safe to read; used only when valid
    int pe = ptot[b]; if (pe > PMAX) pe = PMAX;

    // ---- layer-1 folded weights (8 regs) ----
    float s1 = g1[o] * rsqrtf(v1[o] + 1e-5f);
    float b1f = b1[o] - m1[o] * s1;
    float w1r[8];
    {
        const float4* w14 = (const float4*)(w1 + o * 8);
        float4 a = w14[0], c4 = w14[1];
        w1r[0] = a.x * s1;  w1r[1] = a.y * s1;  w1r[2] = a.z * s1;  w1r[3] = a.w * s1;
        w1r[4] = c4.x * s1; w1r[5] = c4.y * s1; w1r[6] = c4.z * s1; w1r[7] = c4.w * s1;
    }

    // ---- stage folded w2 into LDS ----
    float s2 = g2[o] * rsqrtf(v2[o] + 1e-5f);
    float b2f = b2[o] - m2[o] * s2;
    {
        const float4* w2row = (const float4*)(w2 + o * 64);
        #pragma unroll
        for (int it = 0; it < 4; ++it) {
            int kq = widx + it * 4;
            float4 t = w2row[kq];
            t.x *= s2; t.y *= s2; t.z *= s2; t.w *= s2;
            w2s[kq * 64 + o] = t;
        }
    }
    __syncthreads();   // one-time; all waves converged

    size_t frow = (size_t)p * 64;
    size_t crow = (size_t)p * 3;

    if (r >= pe) {
        feats[frow + o] = 0.0f;
        if (o < 3) coords[crow + o] = (o == 0) ? (float)b : 0.0f;
        return;
    }

    int key = meta.x, c = meta.y;
    int xi = key / NYG;
    int yi = key - xi * NYG;
    float xc = (float)xi * 0.16f - 40.0f + 0.08f;
    float yc = (float)yi * 0.16f - 40.0f + 0.08f;

    int pc = (c < T_SLOTS) ? c : T_SLOTS;
    int nIter = pc + ((c < T_SLOTS) ? 1 : 0);   // + empty-slot feature unless full

    float acc = 0.0f;   // slot outputs are post-ReLU (>=0)
    for (int s = 0; s < nIter; ++s) {
        float4 P;
        if (s < pc) {
            int j = (s == 0) ? j4.x : (s == 1) ? j4.y : (s == 2) ? j4.z
                  : (s == 3) ? j4.w : prow[s];
            P = pts4[(size_t)b * NPTS + j];
        } else {
            P.x = 0.0f; P.y = 0.0f; P.z = 0.0f; P.w = 0.0f;
        }
        float h = b1f;
        h += w1r[0] * P.x; h += w1r[1] * P.y;
        h += w1r[2] * P.z; h += w1r[3] * P.w;
        h += w1r[4] * xc;  h += w1r[5] * yc;
        h += w1r[6] * (P.x - xc); h += w1r[7] * (P.y - yc);
        h = fmaxf(h, 0.0f);

        // wave-local h1 broadcast via LDS (wave-synchronous; DS pipe in-order)
        h1s[widx][o] = h;
        asm volatile("s_waitcnt lgkmcnt(0)" ::: "memory");

        float a0 = b2f, a1 = 0.0f, a2 = 0.0f, a3 = 0.0f;
        #pragma unroll
        for (int kq = 0; kq < 16; ++kq) {
            float4 w  = w2s[kq * 64 + o];
            float4 hb = *(const float4*)&h1s[widx][kq * 4];
            a0 += w.x * hb.x; a1 += w.y * hb.y;
            a2 += w.z * hb.z; a3 += w.w * hb.w;
        }
        float h2 = fmaxf((a0 + a1) + (a2 + a3), 0.0f);
        acc = fmaxf(acc, h2);
    }

    feats[frow + o] = acc;
    if (o < 3)
        coords[crow + o] = (o == 0) ? (float)b : ((o == 1) ? (float)xi : (float)yi);
}

// ---------------- launcher ----------------

extern "C" void kernel_launch(void* const* d_in, const int* in_sizes, int n_in,
                              void* d_out, int out_size, void* d_ws, size_t ws_size,
                              hipStream_t stream) {
    if (ws_size < WS_NEEDED) return;   // safety: avoid scratch corruption

    const float* pts = (const float*)d_in[0];
    const float* w1  = (const float*)d_in[1];
    const float* g1  = (const float*)d_in[2];
    const float* b1  = (const float*)d_in[3];
    const float* m1  = (const float*)d_in[4];
    const float* v1  = (const float*)d_in[5];
    const float* w2  = (const float*)d_in[6];
    const float* g2  = (const float*)d_in[7];
    const float* b2  = (const float*)d_in[8];
    const float* m2  = (const float*)d_in[9];
    const float* v2  = (const float*)d_in[10];

    char* ws = (char*)d_ws;
    int*  cnt     = (int*)(ws + WS_CNT);
    int*  slotctr = (int*)(ws + WS_SLOT);
    int*  rank    = (int*)(ws + WS_RANK);
    int*  keypt   = (int*)(ws + WS_KEYPT);
    int2* pmeta   = (int2*)(ws + WS_PMETA);
    int*  pidx    = (int*)(ws + WS_PIDX);
    int*  bsum    = (int*)(ws + WS_BSUM);
    int*  ptot    = (int*)(ws + WS_PTOT);

    float* out = (float*)d_out;

    hipLaunchKernelGGL(k_zero, dim3((ZERO_F4 + 255) / 256), dim3(256), 0, stream,
                       (float4*)(ws + WS_CNT));

    int npt = NBATCH * NPTS;
    dim3 blk256(256);
    dim3 grdPts((npt + 255) / 256);
    hipLaunchKernelGGL(k_key, grdPts, blk256, 0, stream, pts, keypt, cnt);

    dim3 grdScan(NBLK, NBATCH);
    hipLaunchKernelGGL(k_scan1, grdScan, dim3(SCAN_B), 0, stream, cnt, bsum);
    hipLaunchKernelGGL(k_scan23, grdScan, dim3(SCAN_B), 0, stream, cnt, bsum, rank, ptot);

    hipLaunchKernelGGL(k_fill, grdPts, blk256, 0, stream,
                       keypt, cnt, rank, slotctr, pmeta, pidx);

    hipLaunchKernelGGL(k_feats, dim3(FEAT_BLOCKS), blk256, 0, stream,
                       (const float4*)pts, w1, g1, b1, m1, v1, w2, g2, b2, m2, v2,
                       pmeta, pidx, ptot, out);
}